// Round 5
// baseline (136.831 us; speedup 1.0000x reference)
//
#include <hip/hip_runtime.h>
#include <stdint.h>

#define N 2048
#define TILE 128
#define BK 64
#define KH 16            // K-steps per half-pipeline (2 halves x 16 = 32 total)
#define LDSW 72          // u16 row stride: 144 B rows; 16B-aligned b128, min-phase banking
#define RSTR 33          // f32 row stride for the K-half exchange slots
#define NN ((size_t)N * (size_t)N)

typedef unsigned short u16;
typedef __bf16 bf16x8 __attribute__((ext_vector_type(8)));
typedef unsigned short ushortx8 __attribute__((ext_vector_type(8)));
typedef float floatx4 __attribute__((ext_vector_type(4)));

static __device__ __forceinline__ u16 f2bf(float f) {
  unsigned int u = __builtin_bit_cast(unsigned int, f);
  return (u16)((u + 0x7fffu + ((u >> 16) & 1u)) >> 16);  // RNE, finite inputs
}

// ---------------------------------------------------------------------------
// cast + transpose: Ab[r][c] = bf16(A[r][c]); Abt[c][r] = bf16(A[r][c]);
// block (0,0) also zeroes the fused-rowsum accumulator.
// ---------------------------------------------------------------------------
__global__ void cast_tr(const float* __restrict__ A, u16* __restrict__ Ab,
                        u16* __restrict__ Abt, float* __restrict__ rsum) {
  __shared__ float tile[32][33];
  const int tx = threadIdx.x, ty = threadIdx.y;
  if (blockIdx.x == 0 && blockIdx.y == 0) {
    const int tid = ty * 32 + tx;
    for (int k = tid; k < N; k += 256) rsum[k] = 0.f;
  }
  const int c = blockIdx.x * 32 + tx;
#pragma unroll
  for (int i = 0; i < 4; i++) {
    const int r = blockIdx.y * 32 + ty + i * 8;
    const float v = A[(size_t)r * N + c];
    Ab[(size_t)r * N + c] = f2bf(v);
    tile[ty + i * 8][tx] = v;
  }
  __syncthreads();
  const int r2 = blockIdx.y * 32 + tx;
#pragma unroll
  for (int i = 0; i < 4; i++) {
    const int c2 = blockIdx.x * 32 + ty + i * 8;
    Abt[(size_t)c2 * N + r2] = f2bf(tile[tx][ty + i * 8]);
  }
}

// ---------------------------------------------------------------------------
// GEMM core: C = L[128 x N] * R[N x 128] (Rt stored [n][k]).
// 512 threads = 8 waves = 4 output positions x in-block split-K-2.
// Round-4 post-mortem: 64x32 wave tiles are LDS-read-bound (768 B frag read
// per MFMA; LDS pipe ~2300 cyc/step vs MFMA 310). 64x64 wave tiles cut that
// to 512 B/MFMA (frag instrs/step 192->128) and double per-wave MFMA ILP.
// Wave w: sub = w&3 -> (wr,wc) = ((sub>>1)*64, (sub&1)*64); h = w>>2 is the
// K-half: h processes K in [h*1024, (h+1)*1024) in its own double-buffered
// pipeline; halves share the block barrier in lockstep (one barrier/step,
// proven rounds 2-4). Depth-1 register prefetch (panels are L2/L3-warm;
// ~200-300 cyc latency << ~2000 cyc step).
// acc[4][4] = 64 VGPRs; cap 256 at __launch_bounds__(512,2). ALL register
// arrays statically indexed (rule #20 — rounds 1/3 regression).
// Epilogue: K-half exchange through LDS aliasing dead staging buffers;
// result res[4][8] = the 64x32 column block (cols wc+(h*2+j)*16) this wave
// keeps — callers store only that.
// ---------------------------------------------------------------------------
__device__ __forceinline__ void gemm_core(const u16* __restrict__ L,
                                          const u16* __restrict__ Rt,
                                          float res[4][8]) {
  __shared__ __align__(16) u16 As[2][2][TILE * LDSW];  // [half][buf] 73,728 B
  __shared__ __align__(16) u16 Bs[2][2][TILE * LDSW];  // [half][buf] 73,728 B

  const int t = threadIdx.x;             // 0..511
  const int h = t >> 8;                  // K-half (== (t>>6)>>2)
  const int tl = t & 255;
  const int row0 = blockIdx.y * TILE;
  const int col0 = blockIdx.x * TILE;

  // staging map (per half, 256 threads): chunk c covers ci = c*256+tl of the
  // 1024 16B-chunks in a 128x64 tile: row = ci>>3, col16 = ci&7.
  // Per instruction (fixed c): 8-lane 128B segments, min-phase LDS banking.
  int goff[4], woff[4];
#pragma unroll
  for (int c = 0; c < 4; c++) {
    const int rowc = c * 32 + (tl >> 3);
    const int colc = (tl & 7) * 8;
    goff[c] = rowc * N + colc;
    woff[c] = rowc * LDSW + colc;
  }
  const u16* gA = L + (size_t)row0 * N + h * (KH * BK);
  const u16* gB = Rt + (size_t)col0 * N + h * (KH * BK);

  const int lane = t & 63;
  const int w = t >> 6;                  // 0..7
  const int sub = w & 3;
  const int wr = (sub >> 1) * 64;
  const int wc = (sub & 1) * 64;
  const int lr = lane & 15;
  const int q = lane >> 4;
  const int abase = (wr + lr) * LDSW + q * 8;
  const int bbase = (wc + lr) * LDSW + q * 8;

  floatx4 acc[4][4];
#pragma unroll
  for (int i = 0; i < 4; i++)
#pragma unroll
    for (int j = 0; j < 4; j++) acc[i][j] = (floatx4){0.f, 0.f, 0.f, 0.f};

  // prologue: tile 0 of this half -> buf 0
  {
    ushortx8 pa[4], pb[4];
#pragma unroll
    for (int c = 0; c < 4; c++) {
      pa[c] = *(const ushortx8*)(gA + goff[c]);
      pb[c] = *(const ushortx8*)(gB + goff[c]);
    }
#pragma unroll
    for (int c = 0; c < 4; c++) {
      *(ushortx8*)&As[h][0][woff[c]] = pa[c];
      *(ushortx8*)&Bs[h][0][woff[c]] = pb[c];
    }
  }
  __syncthreads();

  // step i: issue global loads for tile i+1; compute on buf[cur]=tile i;
  // publish tile i+1 into buf[nxt]; one barrier. Writes to buf[nxt] are safe:
  // all waves' reads of buf[nxt] (step i-1) were lgkm-drained before the
  // barrier at end of step i-1 (proven rounds 2-4).
#define GSTEP(i, cur, nxt)                                                    \
  {                                                                           \
    ushortx8 pa[4], pb[4];                                                    \
    if ((i) + 1 < KH) {                                                       \
      _Pragma("unroll") for (int c = 0; c < 4; c++) {                         \
        pa[c] = *(const ushortx8*)(gA + goff[c] + ((i) + 1) * BK);            \
        pb[c] = *(const ushortx8*)(gB + goff[c] + ((i) + 1) * BK);            \
      }                                                                       \
    }                                                                         \
    _Pragma("unroll") for (int kk = 0; kk < 2; kk++) {                        \
      bf16x8 af[4], bf[4];                                                    \
      _Pragma("unroll") for (int mt = 0; mt < 4; mt++) af[mt] =               \
          __builtin_bit_cast(bf16x8,                                          \
              *(const ushortx8*)&As[h][cur][abase + kk * 32 + mt * 16 * LDSW]); \
      _Pragma("unroll") for (int nt = 0; nt < 4; nt++) bf[nt] =               \
          __builtin_bit_cast(bf16x8,                                          \
              *(const ushortx8*)&Bs[h][cur][bbase + kk * 32 + nt * 16 * LDSW]); \
      _Pragma("unroll") for (int mt = 0; mt < 4; mt++)                        \
          _Pragma("unroll") for (int nt = 0; nt < 4; nt++) acc[mt][nt] =      \
              __builtin_amdgcn_mfma_f32_16x16x32_bf16(af[mt], bf[nt],         \
                                                      acc[mt][nt], 0, 0, 0);  \
    }                                                                         \
    if ((i) + 1 < KH) {                                                       \
      _Pragma("unroll") for (int c = 0; c < 4; c++) {                         \
        *(ushortx8*)&As[h][nxt][woff[c]] = pa[c];                             \
        *(ushortx8*)&Bs[h][nxt][woff[c]] = pb[c];                             \
      }                                                                       \
    }                                                                         \
    __syncthreads();                                                          \
  }

  for (int io = 0; io < KH; io += 2) {
    GSTEP(io, 0, 1)
    GSTEP(io + 1, 1, 0)
  }
#undef GSTEP

  // K-half exchange. Aliases As (dead after the final barrier: every wave's
  // LDS reads were lgkm-drained before it reached that barrier).
  // Wave (sub,h) keeps cols nt in {2h, 2h+1}; ships nt in {2(1-h), 2(1-h)+1}
  // to slot (sub, 1-h); partner's shipment arrives in slot (sub, h).
  // 8 slots x 64 x RSTR(33) f32 = 67,584 B <= 73,728 B. Static acc indices;
  // h selects VALUES via ternary only (rule #20).
  float* red = (float*)&As[0][0][0];
  const int oh = 1 - h;
  const int rship = (sub * 2 + oh) * (64 * RSTR);
  const int rkeep = (sub * 2 + h) * (64 * RSTR);
#pragma unroll
  for (int mt = 0; mt < 4; mt++)
#pragma unroll
    for (int j = 0; j < 2; j++)
#pragma unroll
      for (int r = 0; r < 4; r++) {
        const float vship = h ? acc[mt][j][r] : acc[mt][j + 2][r];
        red[rship + (mt * 16 + q * 4 + r) * RSTR + j * 16 + lr] = vship;
      }
  __syncthreads();
#pragma unroll
  for (int mt = 0; mt < 4; mt++)
#pragma unroll
    for (int j = 0; j < 2; j++)
#pragma unroll
      for (int r = 0; r < 4; r++) {
        const float vkeep = h ? acc[mt][j + 2][r] : acc[mt][j][r];
        res[mt][j * 4 + r] =
            vkeep + red[rkeep + (mt * 16 + q * 4 + r) * RSTR + j * 16 + lr];
      }
}

// GEMM1: Mb = bf16(A @ A), plus fused f32 row sums of A@A via atomics.
__global__ __launch_bounds__(512, 2) void gemm_aa(const u16* __restrict__ Ab,
                                                  const u16* __restrict__ Abt,
                                                  u16* __restrict__ Mb,
                                                  float* __restrict__ rsum) {
  float res[4][8];
  gemm_core(Ab, Abt, res);
  const int t = threadIdx.x;
  const int lane = t & 63, w = t >> 6;
  const int sub = w & 3, h = w >> 2;
  const int wr = (sub >> 1) * 64, wc = (sub & 1) * 64;
  const int lr = lane & 15, q = lane >> 4;
  const int row0 = blockIdx.y * TILE, col0 = blockIdx.x * TILE;
#pragma unroll
  for (int mt = 0; mt < 4; mt++)
#pragma unroll
    for (int r = 0; r < 4; r++) {
      const int rr = row0 + wr + mt * 16 + q * 4 + r;
      float s = 0.f;
#pragma unroll
      for (int j = 0; j < 2; j++) {
        const float v = res[mt][j * 4 + r];
        s += v;
        const int cc = col0 + wc + (h * 2 + j) * 16 + lr;
        Mb[(size_t)rr * N + cc] = f2bf(v);
      }
      // reduce s over the 16 lr lanes of this q-group (lane bits 0..3)
      s += __shfl_xor(s, 1, 64);
      s += __shfl_xor(s, 2, 64);
      s += __shfl_xor(s, 4, 64);
      s += __shfl_xor(s, 8, 64);
      if (lr == 0) atomicAdd(&rsum[rr], s);  // 32-col partial of this row
    }
}

// GEMM2 + fused norm epilogue: out = (8*(M@A) + 2*A) / (4*rowsum(A@A)+1)
__global__ __launch_bounds__(512, 2) void gemm_ma(const u16* __restrict__ Mb,
                                                  const u16* __restrict__ Abt,
                                                  const float* __restrict__ A,
                                                  const float* __restrict__ rsum,
                                                  float* __restrict__ out) {
  float res[4][8];
  gemm_core(Mb, Abt, res);
  const int t = threadIdx.x;
  const int lane = t & 63, w = t >> 6;
  const int sub = w & 3, h = w >> 2;
  const int wr = (sub >> 1) * 64, wc = (sub & 1) * 64;
  const int lr = lane & 15, q = lane >> 4;
  const int row0 = blockIdx.y * TILE, col0 = blockIdx.x * TILE;
#pragma unroll
  for (int mt = 0; mt < 4; mt++)
#pragma unroll
    for (int r = 0; r < 4; r++) {
      const int rr = row0 + wr + mt * 16 + q * 4 + r;
      float d = 4.f * rsum[rr] + 1.f;
      if (d <= 1e-10f) d = 1.f;
      const float rd = 1.f / d;
#pragma unroll
      for (int j = 0; j < 2; j++) {
        const int cc = col0 + wc + (h * 2 + j) * 16 + lr;
        out[(size_t)rr * N + cc] =
            (8.f * res[mt][j * 4 + r] + 2.f * A[(size_t)rr * N + cc]) * rd;
      }
    }
}

extern "C" void kernel_launch(void* const* d_in, const int* in_sizes, int n_in,
                              void* d_out, int out_size, void* d_ws, size_t ws_size,
                              hipStream_t stream) {
  const float* A = (const float*)d_in[0];
  // GTConv weights (d_in[1..3]) are irrelevant: softmax over a singleton axis
  // is identically 1, so each conv output is exactly 2*A.
  float* out = (float*)d_out;
  char* ws = (char*)d_ws;
  u16* Ab = (u16*)ws;                          // 8 MB bf16 A row-major
  u16* Abt = (u16*)(ws + NN * 2);              // 8 MB bf16 A transposed
  u16* Mb = (u16*)(ws + NN * 4);               // 8 MB bf16 M = A@A
  float* rsum = (float*)(ws + NN * 6);         // 8 KB f32 row sums of M

  cast_tr<<<dim3(N / 32, N / 32), dim3(32, 8), 0, stream>>>(A, Ab, Abt, rsum);
  gemm_aa<<<dim3(N / TILE, N / TILE), 512, 0, stream>>>(Ab, Abt, Mb, rsum);
  gemm_ma<<<dim3(N / TILE, N / TILE), 512, 0, stream>>>(Mb, Abt, A, rsum, out);
}